// Round 9
// baseline (208.392 us; speedup 1.0000x reference)
//
#include <hip/hip_runtime.h>

#define HEADS 8
#define DH 64
#define CO 3
#define E 192
#define NSEQ 2048
#define BATCH 2
#define CIN 256
#define DINNER 512
#define NTOK 4096
#define BHTOT 16

typedef __attribute__((ext_vector_type(8))) short bf16x8;
typedef __attribute__((ext_vector_type(4))) short bf16x4;
typedef __attribute__((ext_vector_type(4))) float f32x4;

static __device__ inline short f2bf(float f) {
  union { float f; unsigned u; } v; v.f = f;
  unsigned r = (v.u + 0x7FFFu + ((v.u >> 16) & 1u)) >> 16;  // RNE
  return (short)r;
}

static __device__ inline void load_lds16(const short* g, short* l) {
  __builtin_amdgcn_global_load_lds(
      (const __attribute__((address_space(1))) void*)g,
      (__attribute__((address_space(3))) void*)l, 16, 0, 0);
}

// Frag-tile packing: a 16(row)x32(k) bf16 MFMA operand tile = 512 shorts,
// element [row r][k = qd*8+j] at (qd*16 + r)*8 + j (consuming wave's lane order).
// Internal e-order: e = c*64 + d.

// ---------------------------------------------------------------- prep_w
__global__ __launch_bounds__(256) void prep_w(const float* __restrict__ Wq,
                                              const float* __restrict__ Wk,
                                              const float* __restrict__ Wv,
                                              const float* __restrict__ Wo,
                                              short* __restrict__ wqkvp,
                                              short* __restrict__ wop) {
  int idx = blockIdx.x * 256 + threadIdx.x;
  const float qscale = 0.07216878364870323f * 1.4426950408889634f;  // 192^-0.5 * log2(e)
  if (idx < 1536 * 256) {
    int o = idx >> 8, i = idx & 255;
    float v;
    if (o < 512) v = Wq[idx] * qscale;
    else if (o < 1024) v = Wk[idx - 512 * 256];
    else v = Wv[idx - 1024 * 256];
    int nt = o >> 4, ln = o & 15, ks = i >> 5, qd = (i >> 3) & 3, j = i & 7;
    wqkvp[((size_t)(nt * 8 + ks)) * 512 + (qd * 16 + ln) * 8 + j] = f2bf(v);
  } else {
    int j0 = idx - 1536 * 256;
    if (j0 < 256 * 512) {
      int o2 = j0 >> 9, i = j0 & 511;
      int nt = o2 >> 4, ln = o2 & 15, ks = i >> 5, qd = (i >> 3) & 3, j = i & 7;
      wop[((size_t)(nt * 16 + ks)) * 512 + (qd * 16 + ln) * 8 + j] = f2bf(Wo[j0]);
    }
  }
}

// ---------------------------------------------------------------- prep_x
__global__ __launch_bounds__(256) void prep_x(const float* __restrict__ x,
                                              short* __restrict__ xcp) {
  int idx = blockIdx.x * 256 + threadIdx.x;  // t*256 + i
  int t = idx >> 8, i = idx & 255;
  const float* p = x + (size_t)idx * 3;
  float a = p[0], b = p[1], c = p[2];
  int mt = t >> 4, ln = t & 15, ks = i >> 5, qd = (i >> 3) & 3, j = i & 7;
  size_t inner = (size_t)(qd * 16 + ln) * 8 + j;
  xcp[((size_t)(0 * 256 + mt) * 8 + ks) * 512 + inner] = f2bf(a);
  xcp[((size_t)(1 * 256 + mt) * 8 + ks) * 512 + inner] = f2bf(b);
  xcp[((size_t)(2 * 256 + mt) * 8 + ks) * 512 + inner] = f2bf(c);
}

// ---------------------------------------------------------------- qkv_gemm
__global__ __launch_bounds__(256, 3) void qkv_gemm(const short* __restrict__ xcp,
                                                   const short* __restrict__ wqkvp,
                                                   short* __restrict__ qp,
                                                   short* __restrict__ kp,
                                                   short* __restrict__ vp) {
  __shared__ __align__(16) short pool[17408];
  int c = blockIdx.z, ntb = blockIdx.x, mtb = blockIdx.y;
  int tid = threadIdx.x, wave = tid >> 6, lane = tid & 63;
  int ln = lane & 15, quad = lane >> 4;
  int wm = wave >> 1, wn = wave & 1;

  const short* gA = xcp + ((size_t)(c * 256 + mtb * 8) * 8) * 512;
  const short* gB = wqkvp + ((size_t)(ntb * 8) * 8) * 512;

  f32x4 acc[4][4] = {};
#pragma unroll
  for (int i = 0; i < 2; i++) {
    int q = tid + 256 * i, mf = q >> 6, l = q & 63;
    load_lds16(gA + (size_t)(mf * 8) * 512 + l * 8, pool + q * 8);
    load_lds16(gB + (size_t)(mf * 8) * 512 + l * 8, pool + 8192 + q * 8);
  }
  for (int ks = 0; ks < 8; ks++) {
    int b = ks & 1;
    __syncthreads();
    if (ks < 7) {
#pragma unroll
      for (int i = 0; i < 2; i++) {
        int q = tid + 256 * i, mf = q >> 6, l = q & 63;
        load_lds16(gA + (size_t)(mf * 8 + ks + 1) * 512 + l * 8, pool + (b ^ 1) * 4096 + q * 8);
        load_lds16(gB + (size_t)(mf * 8 + ks + 1) * 512 + l * 8, pool + 8192 + (b ^ 1) * 4096 + q * 8);
      }
    }
    const short* As = pool + b * 4096;
    const short* Bs = pool + 8192 + b * 4096;
    bf16x8 af[4], bfr[4];
#pragma unroll
    for (int i = 0; i < 4; i++) af[i] = *(const bf16x8*)&As[(wm * 4 + i) * 512 + lane * 8];
#pragma unroll
    for (int j = 0; j < 4; j++) bfr[j] = *(const bf16x8*)&Bs[(wn * 4 + j) * 512 + lane * 8];
#pragma unroll
    for (int i = 0; i < 4; i++)
#pragma unroll
      for (int j = 0; j < 4; j++)
        acc[i][j] = __builtin_amdgcn_mfma_f32_16x16x32_bf16(af[i], bfr[j], acc[i][j], 0, 0, 0);
  }

  int mat = ntb >> 2;
  int b0 = mtb >> 4;
  if (mat < 2) {
    __syncthreads();
    short* tp = pool;  // [128][136]
#pragma unroll
    for (int i = 0; i < 4; i++)
#pragma unroll
      for (int j = 0; j < 4; j++)
#pragma unroll
        for (int jj = 0; jj < 4; jj++)
          tp[(wm * 64 + i * 16 + quad * 4 + jj) * 136 + wn * 64 + j * 16 + ln] =
              f2bf(acc[i][j][jj]);
    __syncthreads();
    short* dst = (mat == 0) ? qp : kp;
    int h0 = (ntb & 3) * 2;
#pragma unroll
    for (int rep = 0; rep < 8; rep++) {
      int gi = rep * 256 + tid;
      int l2 = gi & 15, qd = (gi >> 4) & 3, nf2 = (gi >> 6) & 3,
          esp = (gi >> 8) & 1, hh = (gi >> 9) & 1, kt2 = gi >> 10;
      int tl = kt2 * 64 + nf2 * 16 + l2;
      bf16x8 val = *(const bf16x8*)&tp[tl * 136 + hh * 64 + (esp * 4 + qd) * 8];
      int bhx = b0 * 8 + h0 + hh;
      int kt = (mtb * 2 + kt2) & 31;
      int es = c * 2 + esp;
      size_t off = (((size_t)((bhx * 32 + kt) * 24) + es * 4 + nf2) * 64 +
                    (size_t)(qd * 16 + l2)) * 8;
      *(bf16x8*)(dst + off) = val;
    }
  } else {
#pragma unroll
    for (int i = 0; i < 4; i++) {
      int kt = (mtb * 2 + wm) & 31;
      int ks2 = (i >> 1) & 1;
      int qd2 = (i * 2 + (quad >> 1)) & 3;
#pragma unroll
      for (int j = 0; j < 4; j++) {
        int o = ntb * 128 + wn * 64 + j * 16 + ln;
        int oo = o & 511, h = oo >> 6, d = oo & 63;
        int ef = c * 4 + (d >> 4), l2v = d & 15;
        int bhx = b0 * 8 + h;
        size_t off = ((size_t)((bhx * 32 + kt) * 24 + ks2 * 12 + ef)) * 512 +
                     (qd2 * 16 + l2v) * 8 + (quad & 1) * 4;
        bf16x4 val = { f2bf(acc[i][j][0]), f2bf(acc[i][j][1]),
                       f2bf(acc[i][j][2]), f2bf(acc[i][j][3]) };
        *(bf16x4*)(vp + off) = val;
      }
    }
  }
}

// ---------------------------------------------------------------- attn
// Split-K(3) flash attention (no online max; exp2, log2e folded in Q).
// Grid (48 = bh*3+kh, 16 qt) = 768 blocks = 3/CU. 4 waves x 32 q-rows (R=2).
// LDS 48KB: K|V with P ALIASED into K's region (K dead after QK; barrier (B)
// fences cross-wave K reads from P writes). Register diet for 3 waves/SIMD:
// Q frags re-read per iter from L1/L2 (es-outer loop), exp results packed to
// bf16 in 16 VGPRs before the barrier (s dies pre-barrier).
// R6/R8 bug was HERE: epilogue tp stride 184 < logical row width 192 ->
// row overlap. Stride is now 192 (128*192 = 24576 = exactly the pool).
__global__ __launch_bounds__(256, 3) void attn(const short* __restrict__ qp,
                                               const short* __restrict__ kp,
                                               const short* __restrict__ vp,
                                               short* __restrict__ opart,
                                               float* __restrict__ lpart) {
  __shared__ __align__(16) short pool[24576];  // K 12288 | V 12288; P aliases K
  int pair = blockIdx.x, qt = blockIdx.y;
  int bh = pair / 3, kh = pair - bh * 3;
  int tid = threadIdx.x, wave = tid >> 6, lane = tid & 63;
  int ln = lane & 15, quad = lane >> 4;
  short* Kl = pool;
  short* Vl = pool + 12288;
  short* Pl = pool;  // aliases K region (footprint 128*72=9216 <= 12288)

  int fi0 = wave * 2 + 0, fi1 = wave * 2 + 1;  // 16-row frags in 128-row q-tile
  const short* qb0 = qp +
      ((size_t)(bh * 32 + qt * 2 + (fi0 >> 2)) * 24 + (fi0 & 3)) * 512 + lane * 8;
  const short* qb1 = qp +
      ((size_t)(bh * 32 + qt * 2 + (fi1 >> 2)) * 24 + (fi1 & 3)) * 512 + lane * 8;

  float l_r[2][4] = {};
  f32x4 acc[2][12] = {};
  int kt0 = kh * 11;               // 0,11,22
  int ktn = (kh == 2) ? 10 : 11;   // 11+11+10 = 32
  const short* gKb = kp + (size_t)(bh * 32 + kt0) * 12288;
  const short* gVb = vp + (size_t)(bh * 32 + kt0) * 12288;

  for (int kt = 0; kt < ktn; kt++) {
    const short* gK = gKb + (size_t)kt * 12288;
    const short* gV = gVb + (size_t)kt * 12288;
#pragma unroll
    for (int i = 0; i < 6; i++) {
      load_lds16(gK + (i * 256 + tid) * 8, Kl + (i * 256 + tid) * 8);
      load_lds16(gV + (i * 256 + tid) * 8, Vl + (i * 256 + tid) * 8);
    }
    __syncthreads();  // (A) K/V staged

    // S = Q K^T, es-outer: Q frag loaded once per es (L1-hot), feeds all nf
    f32x4 s[2][4] = {};
#pragma unroll
    for (int es = 0; es < 6; es++) {
      bf16x8 q0 = *(const bf16x8*)(qb0 + es * 2048);
      bf16x8 q1 = *(const bf16x8*)(qb1 + es * 2048);
#pragma unroll
      for (int nf = 0; nf < 4; nf++) {
        bf16x8 kf = *(const bf16x8*)&Kl[(es * 4 + nf) * 512 + lane * 8];
        s[0][nf] = __builtin_amdgcn_mfma_f32_16x16x32_bf16(q0, kf, s[0][nf], 0, 0, 0);
        s[1][nf] = __builtin_amdgcn_mfma_f32_16x16x32_bf16(q1, kf, s[1][nf], 0, 0, 0);
      }
    }

    // exp2 -> packed bf16 in regs (s dies here, before the barrier)
    unsigned pk[2][4][2];
#pragma unroll
    for (int rg = 0; rg < 2; rg++)
#pragma unroll
      for (int nf = 0; nf < 4; nf++)
#pragma unroll
        for (int h2 = 0; h2 < 2; h2++) {
          float pa = __builtin_amdgcn_exp2f(s[rg][nf][h2 * 2 + 0]);
          float pb = __builtin_amdgcn_exp2f(s[rg][nf][h2 * 2 + 1]);
          union { float f; unsigned u; } va, vb;
          va.f = pa; vb.f = pb;
          pk[rg][nf][h2] = ((va.u + 0x8000u) >> 16) |
                           (((vb.u + 0x8000u) >> 16) << 16);
          l_r[rg][h2 * 2 + 0] += pa;
          l_r[rg][h2 * 2 + 1] += pb;
        }

    __syncthreads();  // (B) all waves done reading K; P may overwrite it

#pragma unroll
    for (int rg = 0; rg < 2; rg++)
#pragma unroll
      for (int nf = 0; nf < 4; nf++)
#pragma unroll
        for (int jj = 0; jj < 4; jj++)
          Pl[((wave * 2 + rg) * 16 + quad * 4 + jj) * 72 + nf * 16 + ln] =
              (short)(pk[rg][nf][jj >> 1] >> ((jj & 1) * 16));

    bf16x8 pa[2][2];
#pragma unroll
    for (int rg = 0; rg < 2; rg++) {  // wave-private rows; lgkmcnt orders w->r
      const short* pb = &Pl[((wave * 2 + rg) * 16 + ln) * 72 + quad * 8];
      pa[rg][0] = *(const bf16x8*)pb;
      pa[rg][1] = *(const bf16x8*)(pb + 32);
    }
#pragma unroll
    for (int ef = 0; ef < 12; ef++) {
      bf16x8 v0 = *(const bf16x8*)&Vl[ef * 512 + lane * 8];
      bf16x8 v1 = *(const bf16x8*)&Vl[(12 + ef) * 512 + lane * 8];
#pragma unroll
      for (int rg = 0; rg < 2; rg++) {
        acc[rg][ef] = __builtin_amdgcn_mfma_f32_16x16x32_bf16(pa[rg][0], v0, acc[rg][ef], 0, 0, 0);
        acc[rg][ef] = __builtin_amdgcn_mfma_f32_16x16x32_bf16(pa[rg][1], v1, acc[rg][ef], 0, 0, 0);
      }
    }
    __syncthreads();  // (C) P/V consumed; next iter may restage
  }

#pragma unroll
  for (int rg = 0; rg < 2; rg++)
#pragma unroll
    for (int jj = 0; jj < 4; jj++)
#pragma unroll
      for (int off = 1; off < 16; off <<= 1)
        l_r[rg][jj] += __shfl_xor(l_r[rg][jj], off, 64);

  // epilogue: transpose (UNNORMALIZED) -> contiguous opart rows; store l
  short* tp = pool;  // [128][192]: stride 192 >= logical width 192; fits exactly
#pragma unroll
  for (int rg = 0; rg < 2; rg++)
#pragma unroll
    for (int jj = 0; jj < 4; jj++) {
      int row = (wave * 2 + rg) * 16 + quad * 4 + jj;
#pragma unroll
      for (int ef = 0; ef < 12; ef++)
        tp[row * 192 + ef * 16 + ln] = f2bf(acc[rg][ef][jj]);
    }
  __syncthreads();
  const size_t obase = ((size_t)(kh * 16 + bh) * 2048 + qt * 128) * 192;
#pragma unroll
  for (int rep = 0; rep < 12; rep++) {
    int gi = rep * 256 + tid;           // 128 rows x 24 chunks
    int row = gi / 24, c8 = gi - row * 24;
    *(bf16x8*)(opart + obase + (size_t)row * 192 + c8 * 8) =
        *(const bf16x8*)&tp[row * 192 + c8 * 8];
  }
  int lb = (kh * 16 + bh) * 2048 + qt * 128;
  if (ln == 0) {
#pragma unroll
    for (int rg = 0; rg < 2; rg++)
#pragma unroll
      for (int jj = 0; jj < 4; jj++)
        lpart[lb + (wave * 2 + rg) * 16 + quad * 4 + jj] = l_r[rg][jj];
  }
}

// ---------------------------------------------------------------- merge
// O = (O1+O2+O3)/(l1+l2+l3), written into the packed owp layout.
__global__ __launch_bounds__(256) void merge(const short* __restrict__ opart,
                                             const float* __restrict__ lpart,
                                             short* __restrict__ owp) {
  int G = blockIdx.x * 256 + threadIdx.x;
  int inner = G & 63;
  int ks = (G >> 6) & 15, h = ks >> 1, esp = ks & 1;
  int mt = (G >> 10) & 255;
  int c = G >> 18;
  int row16 = inner & 15, qd = inner >> 4;
  int t = mt * 16 + row16, b = t >> 11, n = t & 2047;
  int bh = b * 8 + h;
  size_t so = ((size_t)bh * 2048 + n) * 192 + c * 64 + esp * 32 + qd * 8;
  const size_t HSTR = (size_t)16 * 2048 * 192;
  float acc[8] = {};
  float l = 0.f;
#pragma unroll
  for (int khp = 0; khp < 3; khp++) {
    bf16x8 o = *(const bf16x8*)(opart + khp * HSTR + so);
#pragma unroll
    for (int j = 0; j < 8; j++) {
      union { unsigned u; float f; } a;
      a.u = ((unsigned)(unsigned short)o[j]) << 16;
      acc[j] += a.f;
    }
    l += lpart[khp * 16 * 2048 + bh * 2048 + n];
  }
  float inv = 1.f / l;
  bf16x8 r;
#pragma unroll
  for (int j = 0; j < 8; j++) r[j] = f2bf(acc[j] * inv);
  *(bf16x8*)(owp + (size_t)G * 8) = r;
}

// ---------------------------------------------------------------- out_gemm
// final[t,o2,c] = sum_i ow[t,c][i]*wo[o2][i], M=4096 N=256 K=512. (R5 form)
__global__ __launch_bounds__(256) void out_gemm(const short* __restrict__ owp,
                                                const short* __restrict__ wop,
                                                float* __restrict__ out) {
  __shared__ __align__(16) short Al[4096], Bl[2048];
  int c = blockIdx.z, ntb = blockIdx.x, mtb = blockIdx.y;
  int tid = threadIdx.x, wave = tid >> 6, lane = tid & 63;
  int ln = lane & 15, quad = lane >> 4;
  int wm = wave >> 1, wn = wave & 1;

  f32x4 acc[4][2] = {};
  const short* gAb = owp + ((size_t)(c * 256 + mtb * 8) * 16) * 512;
  const short* gBb = wop + ((size_t)(ntb * 4) * 16) * 512;
  for (int ks = 0; ks < 16; ks++) {
#pragma unroll
    for (int i = 0; i < 2; i++) {
      int q = tid + 256 * i, mf = q >> 6, l = q & 63;
      load_lds16(gAb + (size_t)(mf * 16 + ks) * 512 + l * 8, &Al[q * 8]);
    }
    {
      int nf2 = tid >> 6;
      load_lds16(gBb + (size_t)(nf2 * 16 + ks) * 512 + lane * 8, &Bl[tid * 8]);
    }
    __syncthreads();
    bf16x8 af[4], bfr[2];
#pragma unroll
    for (int i = 0; i < 4; i++) af[i] = *(const bf16x8*)&Al[(wm * 4 + i) * 512 + lane * 8];
#pragma unroll
    for (int j = 0; j < 2; j++) bfr[j] = *(const bf16x8*)&Bl[(wn * 2 + j) * 512 + lane * 8];
#pragma unroll
    for (int i = 0; i < 4; i++)
#pragma unroll
      for (int j = 0; j < 2; j++)
        acc[i][j] = __builtin_amdgcn_mfma_f32_16x16x32_bf16(af[i], bfr[j], acc[i][j], 0, 0, 0);
    __syncthreads();
  }
#pragma unroll
  for (int i = 0; i < 4; i++) {
#pragma unroll
    for (int j = 0; j < 2; j++) {
      int o2 = ntb * 64 + (wn * 2 + j) * 16 + ln;
#pragma unroll
      for (int jj = 0; jj < 4; jj++) {
        int t = mtb * 128 + (wm * 4 + i) * 16 + quad * 4 + jj;
        out[((size_t)t * 256 + o2) * 3 + c] = acc[i][j][jj];
      }
    }
  }
}

// ---------------------------------------------------------------- launch
extern "C" void kernel_launch(void* const* d_in, const int* in_sizes, int n_in,
                              void* d_out, int out_size, void* d_ws, size_t ws_size,
                              hipStream_t stream) {
  const float* x  = (const float*)d_in[0];
  const float* Wq = (const float*)d_in[1];
  const float* Wk = (const float*)d_in[2];
  const float* Wv = (const float*)d_in[3];
  const float* Wo = (const float*)d_in[4];
  float* out = (float*)d_out;

  // Total = 82.84 MB (< R5-proven 83,099,648 B)
  short* ws    = (short*)d_ws;
  short* xcp   = ws;                                   // 3*4096*256
  short* wqkvp = xcp + 3 * NTOK * CIN;                 // 1536*256
  short* wop   = wqkvp + 1536 * 256;                   // 256*512
  short* qp    = wop + 256 * 512;                      // 16*2048*192
  short* kp    = qp + (size_t)BHTOT * NSEQ * E;
  short* vp    = kp + (size_t)BHTOT * NSEQ * E;
  short* opart = vp + (size_t)BHTOT * NSEQ * E;        // 3*16*2048*192
  float* lpart = (float*)xcp;   // ALIAS: xcp dead after qkv_gemm (stream order)
  short* owp   = qp;            // ALIAS: qp last read in attn; merge writes after

  prep_w<<<2048, 256, 0, stream>>>(Wq, Wk, Wv, Wo, wqkvp, wop);
  prep_x<<<NTOK * CIN / 256, 256, 0, stream>>>(x, xcp);
  qkv_gemm<<<dim3(12, 32, 3), 256, 0, stream>>>(xcp, wqkvp, qp, kp, vp);
  attn<<<dim3(48, 16), 256, 0, stream>>>(qp, kp, vp, opart, lpart);
  merge<<<3072, 256, 0, stream>>>(opart, lpart, owp);
  out_gemm<<<dim3(4, 32, 3), 256, 0, stream>>>(owp, wop, out);
}

// Round 10
// 170.309 us; speedup vs baseline: 1.2236x; 1.2236x over previous
//
#include <hip/hip_runtime.h>

#define HEADS 8
#define DH 64
#define CO 3
#define E 192
#define NSEQ 2048
#define BATCH 2
#define CIN 256
#define DINNER 512
#define NTOK 4096
#define BHTOT 16

typedef __attribute__((ext_vector_type(8))) short bf16x8;
typedef __attribute__((ext_vector_type(4))) short bf16x4;
typedef __attribute__((ext_vector_type(4))) float f32x4;

static __device__ inline short f2bf(float f) {
  union { float f; unsigned u; } v; v.f = f;
  unsigned r = (v.u + 0x7FFFu + ((v.u >> 16) & 1u)) >> 16;  // RNE
  return (short)r;
}

static __device__ inline void load_lds16(const short* g, short* l) {
  __builtin_amdgcn_global_load_lds(
      (const __attribute__((address_space(1))) void*)g,
      (__attribute__((address_space(3))) void*)l, 16, 0, 0);
}

// Frag-tile packing: a 16(row)x32(k) bf16 MFMA operand tile = 512 shorts,
// element [row r][k = qd*8+j] at (qd*16 + r)*8 + j (consuming wave's lane order).
// Internal e-order: e = c*64 + d.

// ---------------------------------------------------------------- prep (fused w+x)
__global__ __launch_bounds__(256) void prep(const float* __restrict__ x,
                                            const float* __restrict__ Wq,
                                            const float* __restrict__ Wk,
                                            const float* __restrict__ Wv,
                                            const float* __restrict__ Wo,
                                            short* __restrict__ xcp,
                                            short* __restrict__ wqkvp,
                                            short* __restrict__ wop) {
  int gid = blockIdx.x * 256 + threadIdx.x;
  if (gid < NTOK * CIN) {                     // ---- prep_x part
    int t = gid >> 8, i = gid & 255;
    const float* p = x + (size_t)gid * 3;
    float a = p[0], b = p[1], c = p[2];
    int mt = t >> 4, ln = t & 15, ks = i >> 5, qd = (i >> 3) & 3, j = i & 7;
    size_t inner = (size_t)(qd * 16 + ln) * 8 + j;
    xcp[((size_t)(0 * 256 + mt) * 8 + ks) * 512 + inner] = f2bf(a);
    xcp[((size_t)(1 * 256 + mt) * 8 + ks) * 512 + inner] = f2bf(b);
    xcp[((size_t)(2 * 256 + mt) * 8 + ks) * 512 + inner] = f2bf(c);
    return;
  }
  int idx = gid - NTOK * CIN;                 // ---- prep_w part
  const float qscale = 0.07216878364870323f * 1.4426950408889634f;  // 192^-0.5 * log2(e)
  if (idx < 1536 * 256) {
    int o = idx >> 8, i = idx & 255;
    float v;
    if (o < 512) v = Wq[idx] * qscale;
    else if (o < 1024) v = Wk[idx - 512 * 256];
    else v = Wv[idx - 1024 * 256];
    int nt = o >> 4, ln = o & 15, ks = i >> 5, qd = (i >> 3) & 3, j = i & 7;
    wqkvp[((size_t)(nt * 8 + ks)) * 512 + (qd * 16 + ln) * 8 + j] = f2bf(v);
  } else {
    int j0 = idx - 1536 * 256;
    if (j0 < 256 * 512) {
      int o2 = j0 >> 9, i = j0 & 511;
      int nt = o2 >> 4, ln = o2 & 15, ks = i >> 5, qd = (i >> 3) & 3, j = i & 7;
      wop[((size_t)(nt * 16 + ks)) * 512 + (qd * 16 + ln) * 8 + j] = f2bf(Wo[j0]);
    }
  }
}

// ---------------------------------------------------------------- qkv_gemm
__global__ __launch_bounds__(256, 3) void qkv_gemm(const short* __restrict__ xcp,
                                                   const short* __restrict__ wqkvp,
                                                   short* __restrict__ qp,
                                                   short* __restrict__ kp,
                                                   short* __restrict__ vp) {
  __shared__ __align__(16) short pool[17408];
  int c = blockIdx.z, ntb = blockIdx.x, mtb = blockIdx.y;
  int tid = threadIdx.x, wave = tid >> 6, lane = tid & 63;
  int ln = lane & 15, quad = lane >> 4;
  int wm = wave >> 1, wn = wave & 1;

  const short* gA = xcp + ((size_t)(c * 256 + mtb * 8) * 8) * 512;
  const short* gB = wqkvp + ((size_t)(ntb * 8) * 8) * 512;

  f32x4 acc[4][4] = {};
#pragma unroll
  for (int i = 0; i < 2; i++) {
    int q = tid + 256 * i, mf = q >> 6, l = q & 63;
    load_lds16(gA + (size_t)(mf * 8) * 512 + l * 8, pool + q * 8);
    load_lds16(gB + (size_t)(mf * 8) * 512 + l * 8, pool + 8192 + q * 8);
  }
  for (int ks = 0; ks < 8; ks++) {
    int b = ks & 1;
    __syncthreads();
    if (ks < 7) {
#pragma unroll
      for (int i = 0; i < 2; i++) {
        int q = tid + 256 * i, mf = q >> 6, l = q & 63;
        load_lds16(gA + (size_t)(mf * 8 + ks + 1) * 512 + l * 8, pool + (b ^ 1) * 4096 + q * 8);
        load_lds16(gB + (size_t)(mf * 8 + ks + 1) * 512 + l * 8, pool + 8192 + (b ^ 1) * 4096 + q * 8);
      }
    }
    const short* As = pool + b * 4096;
    const short* Bs = pool + 8192 + b * 4096;
    bf16x8 af[4], bfr[4];
#pragma unroll
    for (int i = 0; i < 4; i++) af[i] = *(const bf16x8*)&As[(wm * 4 + i) * 512 + lane * 8];
#pragma unroll
    for (int j = 0; j < 4; j++) bfr[j] = *(const bf16x8*)&Bs[(wn * 4 + j) * 512 + lane * 8];
#pragma unroll
    for (int i = 0; i < 4; i++)
#pragma unroll
      for (int j = 0; j < 4; j++)
        acc[i][j] = __builtin_amdgcn_mfma_f32_16x16x32_bf16(af[i], bfr[j], acc[i][j], 0, 0, 0);
  }

  int mat = ntb >> 2;
  int b0 = mtb >> 4;
  if (mat < 2) {
    __syncthreads();
    short* tp = pool;  // [128][136]
#pragma unroll
    for (int i = 0; i < 4; i++)
#pragma unroll
      for (int j = 0; j < 4; j++)
#pragma unroll
        for (int jj = 0; jj < 4; jj++)
          tp[(wm * 64 + i * 16 + quad * 4 + jj) * 136 + wn * 64 + j * 16 + ln] =
              f2bf(acc[i][j][jj]);
    __syncthreads();
    short* dst = (mat == 0) ? qp : kp;
    int h0 = (ntb & 3) * 2;
#pragma unroll
    for (int rep = 0; rep < 8; rep++) {
      int gi = rep * 256 + tid;
      int l2 = gi & 15, qd = (gi >> 4) & 3, nf2 = (gi >> 6) & 3,
          esp = (gi >> 8) & 1, hh = (gi >> 9) & 1, kt2 = gi >> 10;
      int tl = kt2 * 64 + nf2 * 16 + l2;
      bf16x8 val = *(const bf16x8*)&tp[tl * 136 + hh * 64 + (esp * 4 + qd) * 8];
      int bhx = b0 * 8 + h0 + hh;
      int kt = (mtb * 2 + kt2) & 31;
      int es = c * 2 + esp;
      size_t off = (((size_t)((bhx * 32 + kt) * 24) + es * 4 + nf2) * 64 +
                    (size_t)(qd * 16 + l2)) * 8;
      *(bf16x8*)(dst + off) = val;
    }
  } else {
#pragma unroll
    for (int i = 0; i < 4; i++) {
      int kt = (mtb * 2 + wm) & 31;
      int ks2 = (i >> 1) & 1;
      int qd2 = (i * 2 + (quad >> 1)) & 3;
#pragma unroll
      for (int j = 0; j < 4; j++) {
        int o = ntb * 128 + wn * 64 + j * 16 + ln;
        int oo = o & 511, h = oo >> 6, d = oo & 63;
        int ef = c * 4 + (d >> 4), l2v = d & 15;
        int bhx = b0 * 8 + h;
        size_t off = ((size_t)((bhx * 32 + kt) * 24 + ks2 * 12 + ef)) * 512 +
                     (qd2 * 16 + l2v) * 8 + (quad & 1) * 4;
        bf16x4 val = { f2bf(acc[i][j][0]), f2bf(acc[i][j][1]),
                       f2bf(acc[i][j][2]), f2bf(acc[i][j][3]) };
        *(bf16x4*)(vp + off) = val;
      }
    }
  }
}

// ---------------------------------------------------------------- attn
// Split-K(2) flash attention, R5-proven structure (no online max; exp2
// softmax, log2e folded into Q). Grid (32 pairs, 16 qt); block = 4 waves x
// 32 q-rows (R=2); LDS 67.6KB -> 2 blocks/CU (register ceiling: acc=96 AGPR
// + qf=48 VGPR caps unified usage at 2 waves/SIMD regardless of LDS).
__global__ __launch_bounds__(256, 2) void attn(const short* __restrict__ qp,
                                               const short* __restrict__ kp,
                                               const short* __restrict__ vp,
                                               short* __restrict__ opart,
                                               float* __restrict__ lpart) {
  __shared__ __align__(16) short pool[33792];  // K 12288 | V 12288 | P [8][16][72]
  int pair = blockIdx.x, qt = blockIdx.y;
  int bh = pair & 15, kh = pair >> 4;
  int tid = threadIdx.x, wave = tid >> 6, lane = tid & 63;
  int ln = lane & 15, quad = lane >> 4;
  short* Kl = pool;
  short* Vl = pool + 12288;
  short* Pl = pool + 24576;

  bf16x8 qf[2][6];
#pragma unroll
  for (int rg = 0; rg < 2; rg++) {
    int fi = wave * 2 + rg;  // 16-row frag 0..7 within the 128-row q-tile
    const short* qb = qp +
        ((size_t)(bh * 32 + qt * 2 + (fi >> 2)) * 24 + (fi & 3)) * 512 + lane * 8;
#pragma unroll
    for (int es = 0; es < 6; es++) qf[rg][es] = *(const bf16x8*)(qb + es * 2048);
  }

  float l_r[2][4] = {};
  f32x4 acc[2][12] = {};
  const short* gKb = kp + (size_t)(bh * 32 + kh * 16) * 12288;
  const short* gVb = vp + (size_t)(bh * 32 + kh * 16) * 12288;

  for (int kt = 0; kt < 16; kt++) {
    const short* gK = gKb + (size_t)kt * 12288;
    const short* gV = gVb + (size_t)kt * 12288;
#pragma unroll
    for (int i = 0; i < 6; i++) {
      load_lds16(gK + (i * 256 + tid) * 8, Kl + (i * 256 + tid) * 8);
      load_lds16(gV + (i * 256 + tid) * 8, Vl + (i * 256 + tid) * 8);
    }
    __syncthreads();

    f32x4 s[2][4];
#pragma unroll
    for (int nf = 0; nf < 4; nf++) {
      f32x4 a0 = {}, a1 = {};
#pragma unroll
      for (int es = 0; es < 6; es++) {
        bf16x8 kf = *(const bf16x8*)&Kl[(es * 4 + nf) * 512 + lane * 8];
        a0 = __builtin_amdgcn_mfma_f32_16x16x32_bf16(qf[0][es], kf, a0, 0, 0, 0);
        a1 = __builtin_amdgcn_mfma_f32_16x16x32_bf16(qf[1][es], kf, a1, 0, 0, 0);
      }
      s[0][nf] = a0; s[1][nf] = a1;
    }

#pragma unroll
    for (int rg = 0; rg < 2; rg++)
#pragma unroll
      for (int jj = 0; jj < 4; jj++)
#pragma unroll
        for (int nf = 0; nf < 4; nf++) {
          float p = __builtin_amdgcn_exp2f(s[rg][nf][jj]);
          union { float f; unsigned u; } v; v.f = p;
          Pl[((wave * 2 + rg) * 16 + quad * 4 + jj) * 72 + nf * 16 + ln] =
              (short)((v.u + 0x8000u) >> 16);
          l_r[rg][jj] += p;  // unrounded: unbiased vs rounded-P sum
        }

    bf16x8 pa[2][2];
#pragma unroll
    for (int rg = 0; rg < 2; rg++) {
      const short* pb = &Pl[((wave * 2 + rg) * 16 + ln) * 72 + quad * 8];
      pa[rg][0] = *(const bf16x8*)pb;
      pa[rg][1] = *(const bf16x8*)(pb + 32);
    }
#pragma unroll
    for (int ef = 0; ef < 12; ef++) {
      bf16x8 v0 = *(const bf16x8*)&Vl[ef * 512 + lane * 8];
      bf16x8 v1 = *(const bf16x8*)&Vl[(12 + ef) * 512 + lane * 8];
#pragma unroll
      for (int rg = 0; rg < 2; rg++) {
        acc[rg][ef] = __builtin_amdgcn_mfma_f32_16x16x32_bf16(pa[rg][0], v0, acc[rg][ef], 0, 0, 0);
        acc[rg][ef] = __builtin_amdgcn_mfma_f32_16x16x32_bf16(pa[rg][1], v1, acc[rg][ef], 0, 0, 0);
      }
    }
    __syncthreads();
  }

#pragma unroll
  for (int rg = 0; rg < 2; rg++)
#pragma unroll
    for (int jj = 0; jj < 4; jj++)
#pragma unroll
      for (int off = 1; off < 16; off <<= 1)
        l_r[rg][jj] += __shfl_xor(l_r[rg][jj], off, 64);

  // epilogue: transpose (UNNORMALIZED) -> contiguous opart rows; store l
  short* tp = pool;  // [128][200] = 25600 <= 33792; stride 200 >= 192 (no overlap)
#pragma unroll
  for (int rg = 0; rg < 2; rg++)
#pragma unroll
    for (int jj = 0; jj < 4; jj++) {
      int row = (wave * 2 + rg) * 16 + quad * 4 + jj;
#pragma unroll
      for (int ef = 0; ef < 12; ef++)
        tp[row * 200 + ef * 16 + ln] = f2bf(acc[rg][ef][jj]);
    }
  __syncthreads();
  const size_t obase = ((size_t)(kh * 16 + bh) * 2048 + qt * 128) * 192;
#pragma unroll
  for (int rep = 0; rep < 12; rep++) {
    int gi = rep * 256 + tid;           // 128 rows x 24 chunks
    int row = gi / 24, c8 = gi - row * 24;
    *(bf16x8*)(opart + obase + (size_t)row * 192 + c8 * 8) =
        *(const bf16x8*)&tp[row * 200 + c8 * 8];
  }
  int lb = (kh * 16 + bh) * 2048 + qt * 128;
  if (ln == 0) {
#pragma unroll
    for (int rg = 0; rg < 2; rg++)
#pragma unroll
      for (int jj = 0; jj < 4; jj++)
        lpart[lb + (wave * 2 + rg) * 16 + quad * 4 + jj] = l_r[rg][jj];
  }
}

// ---------------------------------------------------------------- merge
// O = (O1+O2)/(l1+l2), written straight into the packed owp layout.
__global__ __launch_bounds__(256) void merge(const short* __restrict__ opart,
                                             const float* __restrict__ lpart,
                                             short* __restrict__ owp) {
  int G = blockIdx.x * 256 + threadIdx.x;
  int inner = G & 63, qd = inner >> 4, row16 = inner & 15;
  int ks = (G >> 6) & 15, h = ks >> 1, esp = ks & 1;
  int mt = (G >> 10) & 255;
  int c = G >> 18;
  int t = mt * 16 + row16, b = t >> 11, n = t & 2047;
  int bh = b * 8 + h;
  size_t so = ((size_t)bh * 2048 + n) * 192 + c * 64 + esp * 32 + qd * 8;
  const size_t HSTR = (size_t)16 * 2048 * 192;
  bf16x8 o1 = *(const bf16x8*)(opart + so);
  bf16x8 o2 = *(const bf16x8*)(opart + HSTR + so);
  float l = lpart[bh * 2048 + n] + lpart[32768 + bh * 2048 + n];
  float inv = 1.f / l;
  bf16x8 r;
#pragma unroll
  for (int j = 0; j < 8; j++) {
    union { unsigned u; float f; } a, b2;
    a.u = ((unsigned)(unsigned short)o1[j]) << 16;
    b2.u = ((unsigned)(unsigned short)o2[j]) << 16;
    r[j] = f2bf((a.f + b2.f) * inv);
  }
  *(bf16x8*)(owp + (size_t)G * 8) = r;
}

// ---------------------------------------------------------------- out_gemm
// final[t,o2,c] = sum_i ow[t,c][i]*wo[o2][i], M=4096 N=256 K=512.
// 64x64 block tile (4 waves 2x2, each 32x32), grid (4,64,3)=768 = 3 blocks/CU
// (old 128x64 grid had only 384 blocks = 1.5/CU; this kernel is pure launch/
// latency overhead -- 3.2 GFLOP ~ 1.3us of MFMA -- so resident blocks rule).
__global__ __launch_bounds__(256, 4) void out_gemm(const short* __restrict__ owp,
                                                   const short* __restrict__ wop,
                                                   float* __restrict__ out) {
  __shared__ __align__(16) short Al[2048], Bl[2048];
  int c = blockIdx.z, ntb = blockIdx.x, mtb = blockIdx.y;
  int tid = threadIdx.x, wave = tid >> 6, lane = tid & 63;
  int ln = lane & 15, quad = lane >> 4;
  int wm = wave >> 1, wn = wave & 1;

  f32x4 acc[2][2] = {};
  const short* gAb = owp + ((size_t)(c * 256 + mtb * 4) * 16) * 512;
  const short* gBb = wop + ((size_t)(ntb * 4) * 16) * 512;
  for (int ks = 0; ks < 16; ks++) {
    {
      int mf = tid >> 6, l = tid & 63;
      load_lds16(gAb + (size_t)(mf * 16 + ks) * 512 + l * 8, &Al[tid * 8]);
      load_lds16(gBb + (size_t)(mf * 16 + ks) * 512 + l * 8, &Bl[tid * 8]);
    }
    __syncthreads();
    bf16x8 af[2], bfr[2];
#pragma unroll
    for (int i = 0; i < 2; i++) af[i] = *(const bf16x8*)&Al[(wm * 2 + i) * 512 + lane * 8];
#pragma unroll
    for (int j = 0; j < 2; j++) bfr[j] = *(const bf16x8*)&Bl[(wn * 2 + j) * 512 + lane * 8];
#pragma unroll
    for (int i = 0; i < 2; i++)
#pragma unroll
      for (int j = 0; j < 2; j++)
        acc[i][j] = __builtin_amdgcn_mfma_f32_16x16x32_bf16(af[i], bfr[j], acc[i][j], 0, 0, 0);
    __syncthreads();
  }
#pragma unroll
  for (int i = 0; i < 2; i++) {
#pragma unroll
    for (int j = 0; j < 2; j++) {
      int o2 = ntb * 64 + (wn * 2 + j) * 16 + ln;
#pragma unroll
      for (int jj = 0; jj < 4; jj++) {
        int t = mtb * 64 + (wm * 2 + i) * 16 + quad * 4 + jj;
        out[((size_t)t * 256 + o2) * 3 + c] = acc[i][j][jj];
      }
    }
  }
}

// ---------------------------------------------------------------- launch
extern "C" void kernel_launch(void* const* d_in, const int* in_sizes, int n_in,
                              void* d_out, int out_size, void* d_ws, size_t ws_size,
                              hipStream_t stream) {
  const float* x  = (const float*)d_in[0];
  const float* Wq = (const float*)d_in[1];
  const float* Wk = (const float*)d_in[2];
  const float* Wv = (const float*)d_in[3];
  const float* Wo = (const float*)d_in[4];
  float* out = (float*)d_out;

  short* ws    = (short*)d_ws;
  short* xcp   = ws;                                   // 3*4096*256
  short* wqkvp = xcp + 3 * NTOK * CIN;                 // 1536*256
  short* wop   = wqkvp + 1536 * 256;                   // 256*512
  short* qp    = wop + 256 * 512;                      // 16*2048*192
  short* kp    = qp + (size_t)BHTOT * NSEQ * E;
  short* vp    = kp + (size_t)BHTOT * NSEQ * E;
  short* opart = vp + (size_t)BHTOT * NSEQ * E;        // 2*16*2048*192
  float* lpart = (float*)xcp;   // ALIAS: xcp dead after qkv_gemm (stream order)
  short* owp   = qp;            // ALIAS: qp last read in attn; merge writes after

  prep<<<6144, 256, 0, stream>>>(x, Wq, Wk, Wv, Wo, xcp, wqkvp, wop);
  qkv_gemm<<<dim3(12, 32, 3), 256, 0, stream>>>(xcp, wqkvp, qp, kp, vp);
  attn<<<dim3(32, 16), 256, 0, stream>>>(qp, kp, vp, opart, lpart);
  merge<<<3072, 256, 0, stream>>>(opart, lpart, owp);
  out_gemm<<<dim3(4, 64, 3), 256, 0, stream>>>(owp, wop, out);
}

// Round 11
// 166.547 us; speedup vs baseline: 1.2512x; 1.0226x over previous
//
#include <hip/hip_runtime.h>

#define HEADS 8
#define DH 64
#define CO 3
#define E 192
#define NSEQ 2048
#define BATCH 2
#define CIN 256
#define DINNER 512
#define NTOK 4096
#define BHTOT 16

typedef __attribute__((ext_vector_type(8))) short bf16x8;
typedef __attribute__((ext_vector_type(4))) short bf16x4;
typedef __attribute__((ext_vector_type(4))) float f32x4;

static __device__ inline short f2bf(float f) {
  union { float f; unsigned u; } v; v.f = f;
  unsigned r = (v.u + 0x7FFFu + ((v.u >> 16) & 1u)) >> 16;  // RNE
  return (short)r;
}

static __device__ inline void load_lds16(const short* g, short* l) {
  __builtin_amdgcn_global_load_lds(
      (const __attribute__((address_space(1))) void*)g,
      (__attribute__((address_space(3))) void*)l, 16, 0, 0);
}

// Frag-tile packing: a 16(row)x32(k) bf16 MFMA operand tile = 512 shorts,
// element [row r][k = qd*8+j] at (qd*16 + r)*8 + j (consuming wave's lane order).
// Internal e-order: e = c*64 + d.

// ---------------------------------------------------------------- prep (fused w+x)
__global__ __launch_bounds__(256) void prep(const float* __restrict__ x,
                                            const float* __restrict__ Wq,
                                            const float* __restrict__ Wk,
                                            const float* __restrict__ Wv,
                                            const float* __restrict__ Wo,
                                            short* __restrict__ xcp,
                                            short* __restrict__ wqkvp,
                                            short* __restrict__ wop) {
  int gid = blockIdx.x * 256 + threadIdx.x;
  if (gid < NTOK * CIN) {                     // ---- prep_x part
    int t = gid >> 8, i = gid & 255;
    const float* p = x + (size_t)gid * 3;
    float a = p[0], b = p[1], c = p[2];
    int mt = t >> 4, ln = t & 15, ks = i >> 5, qd = (i >> 3) & 3, j = i & 7;
    size_t inner = (size_t)(qd * 16 + ln) * 8 + j;
    xcp[((size_t)(0 * 256 + mt) * 8 + ks) * 512 + inner] = f2bf(a);
    xcp[((size_t)(1 * 256 + mt) * 8 + ks) * 512 + inner] = f2bf(b);
    xcp[((size_t)(2 * 256 + mt) * 8 + ks) * 512 + inner] = f2bf(c);
    return;
  }
  int idx = gid - NTOK * CIN;                 // ---- prep_w part
  const float qscale = 0.07216878364870323f * 1.4426950408889634f;  // 192^-0.5 * log2(e)
  if (idx < 1536 * 256) {
    int o = idx >> 8, i = idx & 255;
    float v;
    if (o < 512) v = Wq[idx] * qscale;
    else if (o < 1024) v = Wk[idx - 512 * 256];
    else v = Wv[idx - 1024 * 256];
    int nt = o >> 4, ln = o & 15, ks = i >> 5, qd = (i >> 3) & 3, j = i & 7;
    wqkvp[((size_t)(nt * 8 + ks)) * 512 + (qd * 16 + ln) * 8 + j] = f2bf(v);
  } else {
    int j0 = idx - 1536 * 256;
    if (j0 < 256 * 512) {
      int o2 = j0 >> 9, i = j0 & 511;
      int nt = o2 >> 4, ln = o2 & 15, ks = i >> 5, qd = (i >> 3) & 3, j = i & 7;
      wop[((size_t)(nt * 16 + ks)) * 512 + (qd * 16 + ln) * 8 + j] = f2bf(Wo[j0]);
    }
  }
}

// ---------------------------------------------------------------- qkv_gemm
// Per c: OUT[t,o] = sum_i xc[t][i]*wqkv[o][i], M=4096 N=1536 K=256.
// v2: B-frags read DIRECT from global (wqkvp = 0.75 MB/c, L2-resident,
// frag-packed -> one global_load_dwordx4 per frag). Only A staged in LDS
// (8 KB/iter, double-buffered). Halves per-iter barrier-drain bytes and
// lifts occupancy to 4 blocks/CU (LDS 34 KB incl. epilogue pool, regs<=128).
__global__ __launch_bounds__(256, 4) void qkv_gemm(const short* __restrict__ xcp,
                                                   const short* __restrict__ wqkvp,
                                                   short* __restrict__ qp,
                                                   short* __restrict__ kp,
                                                   short* __restrict__ vp) {
  __shared__ __align__(16) short pool[17408];  // A dbuf 2x4096 | epilogue tp [128][136]
  int c = blockIdx.z, ntb = blockIdx.x, mtb = blockIdx.y;
  int tid = threadIdx.x, wave = tid >> 6, lane = tid & 63;
  int ln = lane & 15, quad = lane >> 4;
  int wm = wave >> 1, wn = wave & 1;

  const short* gA = xcp + ((size_t)(c * 256 + mtb * 8) * 8) * 512;
  const short* gB = wqkvp + ((size_t)(ntb * 8) * 8) * 512;

  f32x4 acc[4][4] = {};
#pragma unroll
  for (int i = 0; i < 2; i++) {  // stage ks=0 -> buf0
    int q = tid + 256 * i, mf = q >> 6, l = q & 63;
    load_lds16(gA + (size_t)(mf * 8) * 512 + l * 8, pool + q * 8);
  }
  for (int ks = 0; ks < 8; ks++) {
    int b = ks & 1;
    __syncthreads();
    if (ks < 7) {
#pragma unroll
      for (int i = 0; i < 2; i++) {
        int q = tid + 256 * i, mf = q >> 6, l = q & 63;
        load_lds16(gA + (size_t)(mf * 8 + ks + 1) * 512 + l * 8,
                   pool + (b ^ 1) * 4096 + q * 8);
      }
    }
    const short* As = pool + b * 4096;
    bf16x8 af[4], bfr[4];
#pragma unroll
    for (int j = 0; j < 4; j++)
      bfr[j] = *(const bf16x8*)(gB + (size_t)((wn * 4 + j) * 8 + ks) * 512 + lane * 8);
#pragma unroll
    for (int i = 0; i < 4; i++) af[i] = *(const bf16x8*)&As[(wm * 4 + i) * 512 + lane * 8];
#pragma unroll
    for (int i = 0; i < 4; i++)
#pragma unroll
      for (int j = 0; j < 4; j++)
        acc[i][j] = __builtin_amdgcn_mfma_f32_16x16x32_bf16(af[i], bfr[j], acc[i][j], 0, 0, 0);
  }

  int mat = ntb >> 2;
  int b0 = mtb >> 4;
  if (mat < 2) {
    __syncthreads();
    short* tp = pool;  // [128][136]
#pragma unroll
    for (int i = 0; i < 4; i++)
#pragma unroll
      for (int j = 0; j < 4; j++)
#pragma unroll
        for (int jj = 0; jj < 4; jj++)
          tp[(wm * 64 + i * 16 + quad * 4 + jj) * 136 + wn * 64 + j * 16 + ln] =
              f2bf(acc[i][j][jj]);
    __syncthreads();
    short* dst = (mat == 0) ? qp : kp;
    int h0 = (ntb & 3) * 2;
#pragma unroll
    for (int rep = 0; rep < 8; rep++) {
      int gi = rep * 256 + tid;
      int l2 = gi & 15, qd = (gi >> 4) & 3, nf2 = (gi >> 6) & 3,
          esp = (gi >> 8) & 1, hh = (gi >> 9) & 1, kt2 = gi >> 10;
      int tl = kt2 * 64 + nf2 * 16 + l2;
      bf16x8 val = *(const bf16x8*)&tp[tl * 136 + hh * 64 + (esp * 4 + qd) * 8];
      int bhx = b0 * 8 + h0 + hh;
      int kt = (mtb * 2 + kt2) & 31;
      int es = c * 2 + esp;
      size_t off = (((size_t)((bhx * 32 + kt) * 24) + es * 4 + nf2) * 64 +
                    (size_t)(qd * 16 + l2)) * 8;
      *(bf16x8*)(dst + off) = val;
    }
  } else {
#pragma unroll
    for (int i = 0; i < 4; i++) {
      int kt = (mtb * 2 + wm) & 31;
      int ks2 = (i >> 1) & 1;
      int qd2 = (i * 2 + (quad >> 1)) & 3;
#pragma unroll
      for (int j = 0; j < 4; j++) {
        int o = ntb * 128 + wn * 64 + j * 16 + ln;
        int oo = o & 511, h = oo >> 6, d = oo & 63;
        int ef = c * 4 + (d >> 4), l2v = d & 15;
        int bhx = b0 * 8 + h;
        size_t off = ((size_t)((bhx * 32 + kt) * 24 + ks2 * 12 + ef)) * 512 +
                     (qd2 * 16 + l2v) * 8 + (quad & 1) * 4;
        bf16x4 val = { f2bf(acc[i][j][0]), f2bf(acc[i][j][1]),
                       f2bf(acc[i][j][2]), f2bf(acc[i][j][3]) };
        *(bf16x4*)(vp + off) = val;
      }
    }
  }
}

// ---------------------------------------------------------------- attn
// Split-K(2) flash attention, R5-proven structure (no online max; exp2
// softmax, log2e folded into Q). Grid (32 pairs, 16 qt); block = 4 waves x
// 32 q-rows (R=2); LDS 67.6KB -> 2 blocks/CU (register ceiling: acc=96 AGPR
// + qf=48 VGPR caps unified usage at 2 waves/SIMD regardless of LDS).
__global__ __launch_bounds__(256, 2) void attn(const short* __restrict__ qp,
                                               const short* __restrict__ kp,
                                               const short* __restrict__ vp,
                                               short* __restrict__ opart,
                                               float* __restrict__ lpart) {
  __shared__ __align__(16) short pool[33792];  // K 12288 | V 12288 | P [8][16][72]
  int pair = blockIdx.x, qt = blockIdx.y;
  int bh = pair & 15, kh = pair >> 4;
  int tid = threadIdx.x, wave = tid >> 6, lane = tid & 63;
  int ln = lane & 15, quad = lane >> 4;
  short* Kl = pool;
  short* Vl = pool + 12288;
  short* Pl = pool + 24576;

  bf16x8 qf[2][6];
#pragma unroll
  for (int rg = 0; rg < 2; rg++) {
    int fi = wave * 2 + rg;  // 16-row frag 0..7 within the 128-row q-tile
    const short* qb = qp +
        ((size_t)(bh * 32 + qt * 2 + (fi >> 2)) * 24 + (fi & 3)) * 512 + lane * 8;
#pragma unroll
    for (int es = 0; es < 6; es++) qf[rg][es] = *(const bf16x8*)(qb + es * 2048);
  }

  float l_r[2][4] = {};
  f32x4 acc[2][12] = {};
  const short* gKb = kp + (size_t)(bh * 32 + kh * 16) * 12288;
  const short* gVb = vp + (size_t)(bh * 32 + kh * 16) * 12288;

  for (int kt = 0; kt < 16; kt++) {
    const short* gK = gKb + (size_t)kt * 12288;
    const short* gV = gVb + (size_t)kt * 12288;
#pragma unroll
    for (int i = 0; i < 6; i++) {
      load_lds16(gK + (i * 256 + tid) * 8, Kl + (i * 256 + tid) * 8);
      load_lds16(gV + (i * 256 + tid) * 8, Vl + (i * 256 + tid) * 8);
    }
    __syncthreads();

    f32x4 s[2][4];
#pragma unroll
    for (int nf = 0; nf < 4; nf++) {
      f32x4 a0 = {}, a1 = {};
#pragma unroll
      for (int es = 0; es < 6; es++) {
        bf16x8 kf = *(const bf16x8*)&Kl[(es * 4 + nf) * 512 + lane * 8];
        a0 = __builtin_amdgcn_mfma_f32_16x16x32_bf16(qf[0][es], kf, a0, 0, 0, 0);
        a1 = __builtin_amdgcn_mfma_f32_16x16x32_bf16(qf[1][es], kf, a1, 0, 0, 0);
      }
      s[0][nf] = a0; s[1][nf] = a1;
    }

#pragma unroll
    for (int rg = 0; rg < 2; rg++)
#pragma unroll
      for (int jj = 0; jj < 4; jj++)
#pragma unroll
        for (int nf = 0; nf < 4; nf++) {
          float p = __builtin_amdgcn_exp2f(s[rg][nf][jj]);
          union { float f; unsigned u; } v; v.f = p;
          Pl[((wave * 2 + rg) * 16 + quad * 4 + jj) * 72 + nf * 16 + ln] =
              (short)((v.u + 0x8000u) >> 16);
          l_r[rg][jj] += p;  // unrounded: unbiased vs rounded-P sum
        }

    bf16x8 pa[2][2];
#pragma unroll
    for (int rg = 0; rg < 2; rg++) {
      const short* pb = &Pl[((wave * 2 + rg) * 16 + ln) * 72 + quad * 8];
      pa[rg][0] = *(const bf16x8*)pb;
      pa[rg][1] = *(const bf16x8*)(pb + 32);
    }
#pragma unroll
    for (int ef = 0; ef < 12; ef++) {
      bf16x8 v0 = *(const bf16x8*)&Vl[ef * 512 + lane * 8];
      bf16x8 v1 = *(const bf16x8*)&Vl[(12 + ef) * 512 + lane * 8];
#pragma unroll
      for (int rg = 0; rg < 2; rg++) {
        acc[rg][ef] = __builtin_amdgcn_mfma_f32_16x16x32_bf16(pa[rg][0], v0, acc[rg][ef], 0, 0, 0);
        acc[rg][ef] = __builtin_amdgcn_mfma_f32_16x16x32_bf16(pa[rg][1], v1, acc[rg][ef], 0, 0, 0);
      }
    }
    __syncthreads();
  }

#pragma unroll
  for (int rg = 0; rg < 2; rg++)
#pragma unroll
    for (int jj = 0; jj < 4; jj++)
#pragma unroll
      for (int off = 1; off < 16; off <<= 1)
        l_r[rg][jj] += __shfl_xor(l_r[rg][jj], off, 64);

  // epilogue: transpose (UNNORMALIZED) -> contiguous opart rows; store l
  short* tp = pool;  // [128][200] = 25600 <= 33792; stride 200 >= 192 (no overlap)
#pragma unroll
  for (int rg = 0; rg < 2; rg++)
#pragma unroll
    for (int jj = 0; jj < 4; jj++) {
      int row = (wave * 2 + rg) * 16 + quad * 4 + jj;
#pragma unroll
      for (int ef = 0; ef < 12; ef++)
        tp[row * 200 + ef * 16 + ln] = f2bf(acc[rg][ef][jj]);
    }
  __syncthreads();
  const size_t obase = ((size_t)(kh * 16 + bh) * 2048 + qt * 128) * 192;
#pragma unroll
  for (int rep = 0; rep < 12; rep++) {
    int gi = rep * 256 + tid;           // 128 rows x 24 chunks
    int row = gi / 24, c8 = gi - row * 24;
    *(bf16x8*)(opart + obase + (size_t)row * 192 + c8 * 8) =
        *(const bf16x8*)&tp[row * 200 + c8 * 8];
  }
  int lb = (kh * 16 + bh) * 2048 + qt * 128;
  if (ln == 0) {
#pragma unroll
    for (int rg = 0; rg < 2; rg++)
#pragma unroll
      for (int jj = 0; jj < 4; jj++)
        lpart[lb + (wave * 2 + rg) * 16 + quad * 4 + jj] = l_r[rg][jj];
  }
}

// ---------------------------------------------------------------- merge
// O = (O1+O2)/(l1+l2), written straight into the packed owp layout.
__global__ __launch_bounds__(256) void merge(const short* __restrict__ opart,
                                             const float* __restrict__ lpart,
                                             short* __restrict__ owp) {
  int G = blockIdx.x * 256 + threadIdx.x;
  int inner = G & 63, qd = inner >> 4, row16 = inner & 15;
  int ks = (G >> 6) & 15, h = ks >> 1, esp = ks & 1;
  int mt = (G >> 10) & 255;
  int c = G >> 18;
  int t = mt * 16 + row16, b = t >> 11, n = t & 2047;
  int bh = b * 8 + h;
  size_t so = ((size_t)bh * 2048 + n) * 192 + c * 64 + esp * 32 + qd * 8;
  const size_t HSTR = (size_t)16 * 2048 * 192;
  bf16x8 o1 = *(const bf16x8*)(opart + so);
  bf16x8 o2 = *(const bf16x8*)(opart + HSTR + so);
  float l = lpart[bh * 2048 + n] + lpart[32768 + bh * 2048 + n];
  float inv = 1.f / l;
  bf16x8 r;
#pragma unroll
  for (int j = 0; j < 8; j++) {
    union { unsigned u; float f; } a, b2;
    a.u = ((unsigned)(unsigned short)o1[j]) << 16;
    b2.u = ((unsigned)(unsigned short)o2[j]) << 16;
    r[j] = f2bf((a.f + b2.f) * inv);
  }
  *(bf16x8*)(owp + (size_t)G * 8) = r;
}

// ---------------------------------------------------------------- out_gemm
// final[t,o2,c] = sum_i ow[t,c][i]*wo[o2][i], M=4096 N=256 K=512.
// 64x64 block tile (4 waves 2x2, each 32x32), grid (4,64,3)=768 = 3 blocks/CU.
__global__ __launch_bounds__(256, 4) void out_gemm(const short* __restrict__ owp,
                                                   const short* __restrict__ wop,
                                                   float* __restrict__ out) {
  __shared__ __align__(16) short Al[2048], Bl[2048];
  int c = blockIdx.z, ntb = blockIdx.x, mtb = blockIdx.y;
  int tid = threadIdx.x, wave = tid >> 6, lane = tid & 63;
  int ln = lane & 15, quad = lane >> 4;
  int wm = wave >> 1, wn = wave & 1;

  f32x4 acc[2][2] = {};
  const short* gAb = owp + ((size_t)(c * 256 + mtb * 4) * 16) * 512;
  const short* gBb = wop + ((size_t)(ntb * 4) * 16) * 512;
  for (int ks = 0; ks < 16; ks++) {
    {
      int mf = tid >> 6, l = tid & 63;
      load_lds16(gAb + (size_t)(mf * 16 + ks) * 512 + l * 8, &Al[tid * 8]);
      load_lds16(gBb + (size_t)(mf * 16 + ks) * 512 + l * 8, &Bl[tid * 8]);
    }
    __syncthreads();
    bf16x8 af[2], bfr[2];
#pragma unroll
    for (int i = 0; i < 2; i++) af[i] = *(const bf16x8*)&Al[(wm * 2 + i) * 512 + lane * 8];
#pragma unroll
    for (int j = 0; j < 2; j++) bfr[j] = *(const bf16x8*)&Bl[(wn * 2 + j) * 512 + lane * 8];
#pragma unroll
    for (int i = 0; i < 2; i++)
#pragma unroll
      for (int j = 0; j < 2; j++)
        acc[i][j] = __builtin_amdgcn_mfma_f32_16x16x32_bf16(af[i], bfr[j], acc[i][j], 0, 0, 0);
    __syncthreads();
  }
#pragma unroll
  for (int i = 0; i < 2; i++) {
#pragma unroll
    for (int j = 0; j < 2; j++) {
      int o2 = ntb * 64 + (wn * 2 + j) * 16 + ln;
#pragma unroll
      for (int jj = 0; jj < 4; jj++) {
        int t = mtb * 64 + (wm * 2 + i) * 16 + quad * 4 + jj;
        out[((size_t)t * 256 + o2) * 3 + c] = acc[i][j][jj];
      }
    }
  }
}

// ---------------------------------------------------------------- launch
extern "C" void kernel_launch(void* const* d_in, const int* in_sizes, int n_in,
                              void* d_out, int out_size, void* d_ws, size_t ws_size,
                              hipStream_t stream) {
  const float* x  = (const float*)d_in[0];
  const float* Wq = (const float*)d_in[1];
  const float* Wk = (const float*)d_in[2];
  const float* Wv = (const float*)d_in[3];
  const float* Wo = (const float*)d_in[4];
  float* out = (float*)d_out;

  short* ws    = (short*)d_ws;
  short* xcp   = ws;                                   // 3*4096*256
  short* wqkvp = xcp + 3 * NTOK * CIN;                 // 1536*256
  short* wop   = wqkvp + 1536 * 256;                   // 256*512
  short* qp    = wop + 256 * 512;                      // 16*2048*192
  short* kp    = qp + (size_t)BHTOT * NSEQ * E;
  short* vp    = kp + (size_t)BHTOT * NSEQ * E;
  short* opart = vp + (size_t)BHTOT * NSEQ * E;        // 2*16*2048*192
  float* lpart = (float*)xcp;   // ALIAS: xcp dead after qkv_gemm (stream order)
  short* owp   = qp;            // ALIAS: qp last read in attn; merge writes after

  prep<<<6144, 256, 0, stream>>>(x, Wq, Wk, Wv, Wo, xcp, wqkvp, wop);
  qkv_gemm<<<dim3(12, 32, 3), 256, 0, stream>>>(xcp, wqkvp, qp, kp, vp);
  attn<<<dim3(32, 16), 256, 0, stream>>>(qp, kp, vp, opart, lpart);
  merge<<<3072, 256, 0, stream>>>(opart, lpart, owp);
  out_gemm<<<dim3(4, 64, 3), 256, 0, stream>>>(owp, wop, out);
}

// Round 12
// 162.750 us; speedup vs baseline: 1.2804x; 1.0233x over previous
//
#include <hip/hip_runtime.h>

#define HEADS 8
#define DH 64
#define CO 3
#define E 192
#define NSEQ 2048
#define BATCH 2
#define CIN 256
#define DINNER 512
#define NTOK 4096
#define BHTOT 16

typedef __attribute__((ext_vector_type(8))) short bf16x8;
typedef __attribute__((ext_vector_type(4))) short bf16x4;
typedef __attribute__((ext_vector_type(4))) float f32x4;
typedef __attribute__((ext_vector_type(4))) float float4v;

static __device__ inline short f2bf(float f) {
  union { float f; unsigned u; } v; v.f = f;
  unsigned r = (v.u + 0x7FFFu + ((v.u >> 16) & 1u)) >> 16;  // RNE
  return (short)r;
}

static __device__ inline float bf2f(short s) {
  union { unsigned u; float f; } a;
  a.u = ((unsigned)(unsigned short)s) << 16;
  return a.f;
}

static __device__ inline void load_lds16(const short* g, short* l) {
  __builtin_amdgcn_global_load_lds(
      (const __attribute__((address_space(1))) void*)g,
      (__attribute__((address_space(3))) void*)l, 16, 0, 0);
}

// Frag-tile packing: a 16(row)x32(k) bf16 MFMA operand tile = 512 shorts,
// element [row r][k = qd*8+j] at (qd*16 + r)*8 + j (consuming wave's lane order).
// Internal e-order: e = c*64 + d.

// ---------------------------------------------------------------- prep
// Blocks 0..255: x-part, one mt (16 tokens) per block. Coalesced float4
// reads (12288 contiguous floats) -> LDS repack -> coalesced bf16x8 writes.
// Blocks 256..2303: w-part (1 MB total, original path).
__global__ __launch_bounds__(256) void prep(const float* __restrict__ x,
                                            const float* __restrict__ Wq,
                                            const float* __restrict__ Wk,
                                            const float* __restrict__ Wv,
                                            const float* __restrict__ Wo,
                                            short* __restrict__ xcp,
                                            short* __restrict__ wqkvp,
                                            short* __restrict__ wop) {
  int tid = threadIdx.x;
  if (blockIdx.x < 256) {
    __shared__ short st[12288];  // [c][ks][512]
    int mt = blockIdx.x;
    const float* xb = x + (size_t)mt * 12288;
#pragma unroll
    for (int r = 0; r < 12; r++) {
      int idx4 = r * 256 + tid;
      float4v v = *(const float4v*)(xb + idx4 * 4);
#pragma unroll
      for (int e = 0; e < 4; e++) {
        int fp = idx4 * 4 + e;           // 0..12287
        int ti = fp / 3, c = fp - ti * 3;
        int tl = ti >> 8, i = ti & 255;
        int ks = i >> 5, qd = (i >> 3) & 3, j = i & 7;
        st[c * 4096 + ks * 512 + (qd * 16 + tl) * 8 + j] = f2bf(v[e]);
      }
    }
    __syncthreads();
    short* dst = xcp;  // tiles (c*256+mt, ks) contiguous over ks
#pragma unroll
    for (int rep = 0; rep < 6; rep++) {
      int g = rep * 256 + tid;           // 1536 chunks of 8
      int c = g >> 9, rem = g & 511;     // rem = ks*64 + chunk
      *(bf16x8*)(dst + ((size_t)(c * 256 + mt) * 8) * 512 + rem * 8) =
          *(const bf16x8*)&st[c * 4096 + rem * 8];
    }
    return;
  }
  int idx = (blockIdx.x - 256) * 256 + tid;   // ---- w-part
  const float qscale = 0.07216878364870323f * 1.4426950408889634f;  // 192^-0.5 * log2(e)
  if (idx < 1536 * 256) {
    int o = idx >> 8, i = idx & 255;
    float v;
    if (o < 512) v = Wq[idx] * qscale;
    else if (o < 1024) v = Wk[idx - 512 * 256];
    else v = Wv[idx - 1024 * 256];
    int nt = o >> 4, ln = o & 15, ks = i >> 5, qd = (i >> 3) & 3, j = i & 7;
    wqkvp[((size_t)(nt * 8 + ks)) * 512 + (qd * 16 + ln) * 8 + j] = f2bf(v);
  } else {
    int j0 = idx - 1536 * 256;
    if (j0 < 256 * 512) {
      int o2 = j0 >> 9, i = j0 & 511;
      int nt = o2 >> 4, ln = o2 & 15, ks = i >> 5, qd = (i >> 3) & 3, j = i & 7;
      wop[((size_t)(nt * 16 + ks)) * 512 + (qd * 16 + ln) * 8 + j] = f2bf(Wo[j0]);
    }
  }
}

// ---------------------------------------------------------------- qkv_gemm
// (R11-proven) B-frags direct from L2-resident wqkvp; A staged/double-buffered.
__global__ __launch_bounds__(256, 4) void qkv_gemm(const short* __restrict__ xcp,
                                                   const short* __restrict__ wqkvp,
                                                   short* __restrict__ qp,
                                                   short* __restrict__ kp,
                                                   short* __restrict__ vp) {
  __shared__ __align__(16) short pool[17408];  // A dbuf 2x4096 | epilogue tp [128][136]
  int c = blockIdx.z, ntb = blockIdx.x, mtb = blockIdx.y;
  int tid = threadIdx.x, wave = tid >> 6, lane = tid & 63;
  int ln = lane & 15, quad = lane >> 4;
  int wm = wave >> 1, wn = wave & 1;

  const short* gA = xcp + ((size_t)(c * 256 + mtb * 8) * 8) * 512;
  const short* gB = wqkvp + ((size_t)(ntb * 8) * 8) * 512;

  f32x4 acc[4][4] = {};
#pragma unroll
  for (int i = 0; i < 2; i++) {
    int q = tid + 256 * i, mf = q >> 6, l = q & 63;
    load_lds16(gA + (size_t)(mf * 8) * 512 + l * 8, pool + q * 8);
  }
  for (int ks = 0; ks < 8; ks++) {
    int b = ks & 1;
    __syncthreads();
    if (ks < 7) {
#pragma unroll
      for (int i = 0; i < 2; i++) {
        int q = tid + 256 * i, mf = q >> 6, l = q & 63;
        load_lds16(gA + (size_t)(mf * 8 + ks + 1) * 512 + l * 8,
                   pool + (b ^ 1) * 4096 + q * 8);
      }
    }
    const short* As = pool + b * 4096;
    bf16x8 af[4], bfr[4];
#pragma unroll
    for (int j = 0; j < 4; j++)
      bfr[j] = *(const bf16x8*)(gB + (size_t)((wn * 4 + j) * 8 + ks) * 512 + lane * 8);
#pragma unroll
    for (int i = 0; i < 4; i++) af[i] = *(const bf16x8*)&As[(wm * 4 + i) * 512 + lane * 8];
#pragma unroll
    for (int i = 0; i < 4; i++)
#pragma unroll
      for (int j = 0; j < 4; j++)
        acc[i][j] = __builtin_amdgcn_mfma_f32_16x16x32_bf16(af[i], bfr[j], acc[i][j], 0, 0, 0);
  }

  int mat = ntb >> 2;
  int b0 = mtb >> 4;
  if (mat < 2) {
    __syncthreads();
    short* tp = pool;  // [128][136]
#pragma unroll
    for (int i = 0; i < 4; i++)
#pragma unroll
      for (int j = 0; j < 4; j++)
#pragma unroll
        for (int jj = 0; jj < 4; jj++)
          tp[(wm * 64 + i * 16 + quad * 4 + jj) * 136 + wn * 64 + j * 16 + ln] =
              f2bf(acc[i][j][jj]);
    __syncthreads();
    short* dst = (mat == 0) ? qp : kp;
    int h0 = (ntb & 3) * 2;
#pragma unroll
    for (int rep = 0; rep < 8; rep++) {
      int gi = rep * 256 + tid;
      int l2 = gi & 15, qd = (gi >> 4) & 3, nf2 = (gi >> 6) & 3,
          esp = (gi >> 8) & 1, hh = (gi >> 9) & 1, kt2 = gi >> 10;
      int tl = kt2 * 64 + nf2 * 16 + l2;
      bf16x8 val = *(const bf16x8*)&tp[tl * 136 + hh * 64 + (esp * 4 + qd) * 8];
      int bhx = b0 * 8 + h0 + hh;
      int kt = (mtb * 2 + kt2) & 31;
      int es = c * 2 + esp;
      size_t off = (((size_t)((bhx * 32 + kt) * 24) + es * 4 + nf2) * 64 +
                    (size_t)(qd * 16 + l2)) * 8;
      *(bf16x8*)(dst + off) = val;
    }
  } else {
#pragma unroll
    for (int i = 0; i < 4; i++) {
      int kt = (mtb * 2 + wm) & 31;
      int ks2 = (i >> 1) & 1;
      int qd2 = (i * 2 + (quad >> 1)) & 3;
#pragma unroll
      for (int j = 0; j < 4; j++) {
        int o = ntb * 128 + wn * 64 + j * 16 + ln;
        int oo = o & 511, h = oo >> 6, d = oo & 63;
        int ef = c * 4 + (d >> 4), l2v = d & 15;
        int bhx = b0 * 8 + h;
        size_t off = ((size_t)((bhx * 32 + kt) * 24 + ks2 * 12 + ef)) * 512 +
                     (qd2 * 16 + l2v) * 8 + (quad & 1) * 4;
        bf16x4 val = { f2bf(acc[i][j][0]), f2bf(acc[i][j][1]),
                       f2bf(acc[i][j][2]), f2bf(acc[i][j][3]) };
        *(bf16x4*)(vp + off) = val;
      }
    }
  }
}

// ---------------------------------------------------------------- attn
// (R5/R10-proven) Split-K(2); no online max; exp2; 2 blocks/CU (reg ceiling).
__global__ __launch_bounds__(256, 2) void attn(const short* __restrict__ qp,
                                               const short* __restrict__ kp,
                                               const short* __restrict__ vp,
                                               short* __restrict__ opart,
                                               float* __restrict__ lpart) {
  __shared__ __align__(16) short pool[33792];  // K 12288 | V 12288 | P [8][16][72]
  int pair = blockIdx.x, qt = blockIdx.y;
  int bh = pair & 15, kh = pair >> 4;
  int tid = threadIdx.x, wave = tid >> 6, lane = tid & 63;
  int ln = lane & 15, quad = lane >> 4;
  short* Kl = pool;
  short* Vl = pool + 12288;
  short* Pl = pool + 24576;

  bf16x8 qf[2][6];
#pragma unroll
  for (int rg = 0; rg < 2; rg++) {
    int fi = wave * 2 + rg;
    const short* qb = qp +
        ((size_t)(bh * 32 + qt * 2 + (fi >> 2)) * 24 + (fi & 3)) * 512 + lane * 8;
#pragma unroll
    for (int es = 0; es < 6; es++) qf[rg][es] = *(const bf16x8*)(qb + es * 2048);
  }

  float l_r[2][4] = {};
  f32x4 acc[2][12] = {};
  const short* gKb = kp + (size_t)(bh * 32 + kh * 16) * 12288;
  const short* gVb = vp + (size_t)(bh * 32 + kh * 16) * 12288;

  for (int kt = 0; kt < 16; kt++) {
    const short* gK = gKb + (size_t)kt * 12288;
    const short* gV = gVb + (size_t)kt * 12288;
#pragma unroll
    for (int i = 0; i < 6; i++) {
      load_lds16(gK + (i * 256 + tid) * 8, Kl + (i * 256 + tid) * 8);
      load_lds16(gV + (i * 256 + tid) * 8, Vl + (i * 256 + tid) * 8);
    }
    __syncthreads();

    f32x4 s[2][4];
#pragma unroll
    for (int nf = 0; nf < 4; nf++) {
      f32x4 a0 = {}, a1 = {};
#pragma unroll
      for (int es = 0; es < 6; es++) {
        bf16x8 kf = *(const bf16x8*)&Kl[(es * 4 + nf) * 512 + lane * 8];
        a0 = __builtin_amdgcn_mfma_f32_16x16x32_bf16(qf[0][es], kf, a0, 0, 0, 0);
        a1 = __builtin_amdgcn_mfma_f32_16x16x32_bf16(qf[1][es], kf, a1, 0, 0, 0);
      }
      s[0][nf] = a0; s[1][nf] = a1;
    }

#pragma unroll
    for (int rg = 0; rg < 2; rg++)
#pragma unroll
      for (int jj = 0; jj < 4; jj++)
#pragma unroll
        for (int nf = 0; nf < 4; nf++) {
          float p = __builtin_amdgcn_exp2f(s[rg][nf][jj]);
          union { float f; unsigned u; } v; v.f = p;
          Pl[((wave * 2 + rg) * 16 + quad * 4 + jj) * 72 + nf * 16 + ln] =
              (short)((v.u + 0x8000u) >> 16);
          l_r[rg][jj] += p;
        }

    bf16x8 pa[2][2];
#pragma unroll
    for (int rg = 0; rg < 2; rg++) {
      const short* pb = &Pl[((wave * 2 + rg) * 16 + ln) * 72 + quad * 8];
      pa[rg][0] = *(const bf16x8*)pb;
      pa[rg][1] = *(const bf16x8*)(pb + 32);
    }
#pragma unroll
    for (int ef = 0; ef < 12; ef++) {
      bf16x8 v0 = *(const bf16x8*)&Vl[ef * 512 + lane * 8];
      bf16x8 v1 = *(const bf16x8*)&Vl[(12 + ef) * 512 + lane * 8];
#pragma unroll
      for (int rg = 0; rg < 2; rg++) {
        acc[rg][ef] = __builtin_amdgcn_mfma_f32_16x16x32_bf16(pa[rg][0], v0, acc[rg][ef], 0, 0, 0);
        acc[rg][ef] = __builtin_amdgcn_mfma_f32_16x16x32_bf16(pa[rg][1], v1, acc[rg][ef], 0, 0, 0);
      }
    }
    __syncthreads();
  }

#pragma unroll
  for (int rg = 0; rg < 2; rg++)
#pragma unroll
    for (int jj = 0; jj < 4; jj++)
#pragma unroll
      for (int off = 1; off < 16; off <<= 1)
        l_r[rg][jj] += __shfl_xor(l_r[rg][jj], off, 64);

  short* tp = pool;  // [128][200] = 25600 <= 33792
#pragma unroll
  for (int rg = 0; rg < 2; rg++)
#pragma unroll
    for (int jj = 0; jj < 4; jj++) {
      int row = (wave * 2 + rg) * 16 + quad * 4 + jj;
#pragma unroll
      for (int ef = 0; ef < 12; ef++)
        tp[row * 200 + ef * 16 + ln] = f2bf(acc[rg][ef][jj]);
    }
  __syncthreads();
  const size_t obase = ((size_t)(kh * 16 + bh) * 2048 + qt * 128) * 192;
#pragma unroll
  for (int rep = 0; rep < 12; rep++) {
    int gi = rep * 256 + tid;
    int row = gi / 24, c8 = gi - row * 24;
    *(bf16x8*)(opart + obase + (size_t)row * 192 + c8 * 8) =
        *(const bf16x8*)&tp[row * 200 + c8 * 8];
  }
  int lb = (kh * 16 + bh) * 2048 + qt * 128;
  if (ln == 0) {
#pragma unroll
    for (int rg = 0; rg < 2; rg++)
#pragma unroll
      for (int jj = 0; jj < 4; jj++)
        lpart[lb + (wave * 2 + rg) * 16 + quad * 4 + jj] = l_r[rg][jj];
  }
}

// ---------------------------------------------------------------- out_gemm
// Fused merge + projection, ntb=1: block = (mt: 16 tokens, c), N=256 whole.
// Prologue reads opart partials ONCE in 128B-contiguous segments, merges +
// normalizes, stores the 16x512 A-tile into LDS in frag layout. K-loop:
// A-frag broadcast from LDS, B-frags direct from L2-resident wop (0.26 MB).
// Grid (256,3) = 768 blocks = 3/CU.
__global__ __launch_bounds__(256, 4) void out_gemm(const short* __restrict__ opart,
                                                   const float* __restrict__ lpart,
                                                   const short* __restrict__ wop,
                                                   float* __restrict__ out) {
  __shared__ __align__(16) short Al[8192];  // 16 ks-tiles x 512
  int mtb = blockIdx.x, c = blockIdx.y;
  int tid = threadIdx.x, wave = tid >> 6, lane = tid & 63;
  int ln = lane & 15, quad = lane >> 4;
  const size_t HSTR = (size_t)16 * 2048 * 192;

  // merge-prologue: 1024 chunks (16 rows x 8 h x 8 d8), each bf16x8
#pragma unroll
  for (int rep = 0; rep < 4; rep++) {
    int g = rep * 256 + tid;
    int d8 = g & 7, h = (g >> 3) & 7, row16 = g >> 6;
    int t = mtb * 16 + row16, b = t >> 11, n = t & 2047;
    int bh = b * 8 + h;
    size_t src = ((size_t)bh * 2048 + n) * 192 + c * 64 + d8 * 8;
    bf16x8 o1 = *(const bf16x8*)(opart + src);
    bf16x8 o2 = *(const bf16x8*)(opart + HSTR + src);
    float l = lpart[bh * 2048 + n] + lpart[32768 + bh * 2048 + n];
    float inv = 1.f / l;
    bf16x8 r;
#pragma unroll
    for (int j = 0; j < 8; j++) r[j] = f2bf((bf2f(o1[j]) + bf2f(o2[j])) * inv);
    int i0 = h * 64 + d8 * 8;
    int ks = i0 >> 5, qd = d8 & 3;
    *(bf16x8*)&Al[ks * 512 + (qd * 16 + row16) * 8] = r;
  }
  __syncthreads();

  f32x4 acc[4] = {};
  for (int ks = 0; ks < 16; ks++) {
    bf16x8 af = *(const bf16x8*)&Al[ks * 512 + lane * 8];
#pragma unroll
    for (int jf = 0; jf < 4; jf++) {
      int nt = wave * 4 + jf;
      bf16x8 bfr = *(const bf16x8*)(wop + (size_t)(nt * 16 + ks) * 512 + lane * 8);
      acc[jf] = __builtin_amdgcn_mfma_f32_16x16x32_bf16(af, bfr, acc[jf], 0, 0, 0);
    }
  }
#pragma unroll
  for (int jf = 0; jf < 4; jf++) {
    int o2 = (wave * 4 + jf) * 16 + ln;
#pragma unroll
    for (int jj = 0; jj < 4; jj++) {
      int t = mtb * 16 + quad * 4 + jj;
      out[((size_t)t * 256 + o2) * 3 + c] = acc[jf][jj];
    }
  }
}

// ---------------------------------------------------------------- launch
extern "C" void kernel_launch(void* const* d_in, const int* in_sizes, int n_in,
                              void* d_out, int out_size, void* d_ws, size_t ws_size,
                              hipStream_t stream) {
  const float* x  = (const float*)d_in[0];
  const float* Wq = (const float*)d_in[1];
  const float* Wk = (const float*)d_in[2];
  const float* Wv = (const float*)d_in[3];
  const float* Wo = (const float*)d_in[4];
  float* out = (float*)d_out;

  short* ws    = (short*)d_ws;
  short* xcp   = ws;                                   // 3*4096*256
  short* wqkvp = xcp + 3 * NTOK * CIN;                 // 1536*256
  short* wop   = wqkvp + 1536 * 256;                   // 256*512
  short* qp    = wop + 256 * 512;                      // 16*2048*192
  short* kp    = qp + (size_t)BHTOT * NSEQ * E;
  short* vp    = kp + (size_t)BHTOT * NSEQ * E;
  short* opart = vp + (size_t)BHTOT * NSEQ * E;        // 2*16*2048*192
  float* lpart = (float*)xcp;   // ALIAS: xcp dead after qkv_gemm (stream order)

  prep<<<2304, 256, 0, stream>>>(x, Wq, Wk, Wv, Wo, xcp, wqkvp, wop);
  qkv_gemm<<<dim3(12, 32, 3), 256, 0, stream>>>(xcp, wqkvp, qp, kp, vp);
  attn<<<dim3(32, 16), 256, 0, stream>>>(qp, kp, vp, opart, lpart);
  out_gemm<<<dim3(256, 3), 256, 0, stream>>>(opart, lpart, wop, out);
}